// Round 10
// baseline (191.289 us; speedup 1.0000x reference)
//
#include <hip/hip_runtime.h>

typedef unsigned long long u64;

// Problem constants (fixed by reference file)
#define N_TRUCK 100000
#define BLK 256
#define NB 256           // buckets per graph
#define NPB 391          // nodes per bucket: ceil(100000/256)
#define NBNPB (NB * NPB) // 100096
#define CAP 8192         // slots per bucket (mean 6250, sigma ~79)
#define PB 512           // placer chunks
#define BLK_PL 512       // place block size
#define QS 4             // quarters per bucket for deg/agg
#define CHUNK_MAX 3136   // >= ceil(E/PB)=3125
#define ROW_MASK 0x1FFFFu
#define LC_SHIFT 17

// ---------------- ws layout (bytes) ----------------
// curT i32[256] @ 0 (1024) | curC i32[256] @ 1024 (1024) | G f32[36] @ 2048
// dis_t @ 4096 | dis_c @ 404096 | s_t @ 804096 | y4 @ 1204096 (1600000)
// xs4 f32x4[100000] @ 2804096 (1600000)
// pT  u32[256*CAP] @ 4404096  (8388608)
// pC8 u64[256*CAP] @ 12792704 (16777216)       ends 29569920
// degT4 f32[4][NBNPB] @ 29569920 (1601536)
// degC4 f32[4][NBNPB] @ 31171456 (1601536)
// sum4  f32[4][NBNPB] @ 32772992 (1601536)
// yp4   f32x4[4][NBNPB] @ 34374528 (6406144)   ends 40780672
#define WS_NEED_NEW 40780672ULL

// ============ place (+G on last block): round-9 proven ============

__global__ __launch_bounds__(BLK_PL, 8)
void k_place(const int* __restrict__ trow, const int* __restrict__ tcol,
             const int* __restrict__ crow, const int* __restrict__ ccol,
             const float* __restrict__ ew, int E_,
             int* __restrict__ curT, int* __restrict__ curC,
             unsigned* __restrict__ pT, u64* __restrict__ pC8,
             const float* __restrict__ Wt, const float* __restrict__ bt,
             const float* __restrict__ Wc, const float* __restrict__ bc,
             const float* __restrict__ wlin, float* __restrict__ G) {
    if (blockIdx.x == PB) {
        int l = threadIdx.x;
        if (l < 64) {
            float acc[21];
#pragma unroll
            for (int k = 0; k < 21; k++) acc[k] = 0.0f;
            for (int h = l; h < 128; h += 64) {
                float m[6] = {Wt[h], bt[h], Wc[h], Wc[128 + h], Wc[256 + h], bc[h]};
                float w = wlin[h];
                int k = 0;
#pragma unroll
                for (int a = 0; a < 6; a++)
#pragma unroll
                    for (int b2 = a; b2 < 6; b2++)
                        acc[k++] += m[a] * m[b2] * w;
            }
            int k = 0;
#pragma unroll
            for (int a = 0; a < 6; a++)
#pragma unroll
                for (int b2 = a; b2 < 6; b2++) {
                    float v = acc[k++];
#pragma unroll
                    for (int off = 32; off; off >>= 1) v += __shfl_down(v, off);
                    if (l == 0) {
                        G[a * 6 + b2] = v;
                        G[b2 * 6 + a] = v;
                    }
                }
        }
        return;
    }

    __shared__ u64 pay8[CHUNK_MAX];          // car payload; truck reuses as u32[]
    __shared__ unsigned char bkt[CHUNK_MAX];
    __shared__ int hT[NB], hC[NB];
    __shared__ int shiftA[NB];
    __shared__ int wsum[8];
    unsigned* pay4 = (unsigned*)pay8;

    const int b = blockIdx.x;
    const int t = threadIdx.x;
    const int lane = t & 63, wv = t >> 6;
    const int chunk = (E_ + PB - 1) / PB;
    const int s0 = b * chunk, s1 = min(E_, s0 + chunk);
    const int n = s1 - s0;

    for (int k = t; k < NB; k += BLK_PL) { hT[k] = 0; hC[k] = 0; }
    __syncthreads();
    for (int j = s0 + t; j < s1; j += BLK_PL) {
        int tc = tcol[j];
        int cc = ccol[j];
        atomicAdd(&hT[tc / NPB], 1);
        atomicAdd(&hC[cc / NPB], 1);
    }
    __syncthreads();

    // truck
    {
        int cntk = 0, inc = 0;
        if (t < NB) {
            cntk = hT[t];
            inc = cntk;
#pragma unroll
            for (int off = 1; off < 64; off <<= 1) {
                int nv = __shfl_up(inc, off);
                if (lane >= off) inc += nv;
            }
            if (lane == 63) wsum[wv] = inc;
        }
        __syncthreads();
        if (t < 4) {
            int pv = wsum[t], pinc = pv;
#pragma unroll
            for (int off = 1; off < 4; off <<= 1) {
                int nv = __shfl_up(pinc, off);
                if (lane >= off) pinc += nv;
            }
            wsum[t] = pinc - pv;
        }
        __syncthreads();
        if (t < NB) {
            int lexcl = (inc - cntk) + wsum[wv];
            int gstart = t * CAP + atomicAdd(&curT[t], cntk);
            hT[t] = lexcl;
            shiftA[t] = gstart - lexcl;
        }
        __syncthreads();
        for (int j = s0 + t; j < s1; j += BLK_PL) {
            int tc = tcol[j];
            int k = tc / NPB;
            int s = atomicAdd(&hT[k], 1);
            pay4[s] = ((unsigned)(tc - k * NPB) << LC_SHIFT) | (unsigned)trow[j];
            bkt[s] = (unsigned char)k;
        }
        __syncthreads();
        for (int s = t; s < n; s += BLK_PL)
            pT[s + shiftA[bkt[s]]] = pay4[s];
        __syncthreads();
    }

    // car
    {
        int cntk = 0, inc = 0;
        if (t < NB) {
            cntk = hC[t];
            inc = cntk;
#pragma unroll
            for (int off = 1; off < 64; off <<= 1) {
                int nv = __shfl_up(inc, off);
                if (lane >= off) inc += nv;
            }
            if (lane == 63) wsum[wv] = inc;
        }
        __syncthreads();
        if (t < 4) {
            int pv = wsum[t], pinc = pv;
#pragma unroll
            for (int off = 1; off < 4; off <<= 1) {
                int nv = __shfl_up(pinc, off);
                if (lane >= off) pinc += nv;
            }
            wsum[t] = pinc - pv;
        }
        __syncthreads();
        if (t < NB) {
            int lexcl = (inc - cntk) + wsum[wv];
            int gstart = t * CAP + atomicAdd(&curC[t], cntk);
            hC[t] = lexcl;
            shiftA[t] = gstart - lexcl;
        }
        __syncthreads();
        for (int j = s0 + t; j < s1; j += BLK_PL) {
            int cc = ccol[j];
            int k = cc / NPB;
            int s = atomicAdd(&hC[k], 1);
            unsigned lo = ((unsigned)(cc - k * NPB) << LC_SHIFT) | (unsigned)crow[j];
            pay8[s] = ((u64)__float_as_uint(ew[j]) << 32) | lo;
            bkt[s] = (unsigned char)k;
        }
        __syncthreads();
        for (int s = t; s < n; s += BLK_PL)
            pC8[s + shiftA[bkt[s]]] = pay8[s];
    }
}

// ============ deg, quarter-split: 2*NB*QS blocks x 256 ============

__global__ __launch_bounds__(256, 8)
void k_deg4(const unsigned* __restrict__ pT, const u64* __restrict__ pC8,
            const int* __restrict__ curT, const int* __restrict__ curC,
            float* __restrict__ degT4, float* __restrict__ degC4) {
    __shared__ float acc[NPB];
    int b = blockIdx.x;
    bool car = b >= NB * QS;
    int bb = car ? b - NB * QS : b;
    int bk = bb >> 2, q = bb & 3;
    int cnt = car ? curC[bk] : curT[bk];
    int qs = (cnt * q) >> 2, qe = (cnt * (q + 1)) >> 2;
    int base = bk * CAP;
    int t = threadIdx.x;
    for (int k = t; k < NPB; k += 256) acc[k] = 0.0f;
    __syncthreads();
    if (car) {
        for (int j = qs + t; j < qe; j += 256) {
            u64 v = pC8[base + j];
            atomicAdd(&acc[((unsigned)v) >> LC_SHIFT], __uint_as_float((unsigned)(v >> 32)));
        }
    } else {
        for (int j = qs + t; j < qe; j += 256)
            atomicAdd(&acc[pT[base + j] >> LC_SHIFT], 1.0f);
    }
    __syncthreads();
    float* dst = (car ? degC4 : degT4) + q * NBNPB + bk * NPB;
    for (int nn = t; nn < NPB; nn += 256) dst[nn] = acc[nn];
}

// ============ fin1: dis_t, dis_c, xs4 (node-parallel) ============

__global__ __launch_bounds__(256, 8)
void k_fin1(const float* __restrict__ degT4, const float* __restrict__ degC4,
            const float* __restrict__ x_car,
            float* __restrict__ dis_t, float* __restrict__ dis_c,
            float4* __restrict__ xs4, int nt, int nc) {
    int i = blockIdx.x * 256 + threadIdx.x;
    if (i < nt)
        dis_t[i] = rsqrtf(degT4[i] + degT4[NBNPB + i] + degT4[2 * NBNPB + i] +
                          degT4[3 * NBNPB + i] + 1.0f);
    if (i < nc) {
        float d = rsqrtf(degC4[i] + degC4[NBNPB + i] + degC4[2 * NBNPB + i] +
                         degC4[3 * NBNPB + i] + 1.0f);
        dis_c[i] = d;
        const float* xn = &x_car[3 * i];
        xs4[i] = make_float4(d * xn[0], d * xn[1], d * xn[2], d);
    }
}

// ============ agg, quarter-split: 2*NB*QS blocks x 256 ============

__global__ __launch_bounds__(256, 8)
void k_agg4(const unsigned* __restrict__ pT, const u64* __restrict__ pC8,
            const int* __restrict__ curT, const int* __restrict__ curC,
            const float* __restrict__ dis_t, const float* __restrict__ dis_c,
            const float4* __restrict__ xs4,
            float* __restrict__ sum4, float4* __restrict__ yp4, int nc) {
    int b = blockIdx.x;
    int t = threadIdx.x;
    if (b < NB * QS) {
        __shared__ float sacc[NPB];
        int bk = b >> 2, q = b & 3;
        int cnt = curT[bk];
        int qs = (cnt * q) >> 2, qe = (cnt * (q + 1)) >> 2;
        int base = bk * CAP;
        for (int k = t; k < NPB; k += 256) sacc[k] = 0.0f;
        __syncthreads();
        for (int j = qs + t; j < qe; j += 256) {
            unsigned v = pT[base + j];
            atomicAdd(&sacc[v >> LC_SHIFT], dis_t[v & ROW_MASK]);
        }
        __syncthreads();
        float* dst = sum4 + q * NBNPB + bk * NPB;
        for (int nn = t; nn < NPB; nn += 256) dst[nn] = sacc[nn];
    } else {
        __shared__ float y[NPB * 5];   // stride 5: avoid stride-4 bank aliasing
        __shared__ float dcl[NPB];
        int bb = b - NB * QS;
        int bk = bb >> 2, q = bb & 3;
        int cnt = curC[bk];
        int qs = (cnt * q) >> 2, qe = (cnt * (q + 1)) >> 2;
        int base = bk * CAP;
        for (int k = t; k < NPB * 5; k += 256) y[k] = 0.0f;
        for (int k = t; k < NPB; k += 256) {
            int node = bk * NPB + k;
            dcl[k] = (node < nc) ? dis_c[node] : 0.0f;
        }
        __syncthreads();
        for (int j = qs + t; j < qe; j += 256) {
            u64 v = pC8[base + j];
            unsigned lo = (unsigned)v;
            float4 xa = xs4[lo & ROW_MASK];        // dis_c[row] pre-folded
            int lc = lo >> LC_SHIFT;
            float na = __uint_as_float((unsigned)(v >> 32)) * dcl[lc];
            atomicAdd(&y[lc * 5 + 0], na * xa.x);
            atomicAdd(&y[lc * 5 + 1], na * xa.y);
            atomicAdd(&y[lc * 5 + 2], na * xa.z);
        }
        __syncthreads();
        float4* dst = yp4 + q * NBNPB + bk * NPB;
        for (int nn = t; nn < NPB; nn += 256)
            dst[nn] = make_float4(y[nn * 5 + 0], y[nn * 5 + 1], y[nn * 5 + 2], 0.0f);
    }
}

// ============ fin2: s_t, y4 (node-parallel) ============

__global__ __launch_bounds__(256, 8)
void k_fin2(const float* __restrict__ sum4, const float4* __restrict__ yp4,
            const float* __restrict__ dis_t, const float* __restrict__ dis_c,
            const float4* __restrict__ xs4,
            float* __restrict__ s_t, float4* __restrict__ y4, int nt, int nc) {
    int i = blockIdx.x * 256 + threadIdx.x;
    if (i < nt) {
        float d = dis_t[i];
        float s = sum4[i] + sum4[NBNPB + i] + sum4[2 * NBNPB + i] + sum4[3 * NBNPB + i];
        s_t[i] = fmaf(d, s, d * d);
    }
    if (i < nc) {
        float4 a0 = yp4[i], a1 = yp4[NBNPB + i];
        float4 a2 = yp4[2 * NBNPB + i], a3 = yp4[3 * NBNPB + i];
        float d = dis_c[i];
        float4 xs = xs4[i];                        // d*x already
        y4[i] = make_float4(a0.x + a1.x + a2.x + a3.x + d * xs.x,
                            a0.y + a1.y + a2.y + a3.y + d * xs.y,
                            a0.z + a1.z + a2.z + a3.z + d * xs.z, 1.0f);
    }
}

// ============ pair scorer ============

__device__ __forceinline__ void load_zf(int i, const float* __restrict__ s_t,
                                        const float4* __restrict__ y4, float z[6]) {
    if (i < N_TRUCK) {
        z[0] = s_t[i]; z[1] = 1.0f; z[2] = 0.0f; z[3] = 0.0f; z[4] = 0.0f; z[5] = 0.0f;
    } else {
        float4 y = y4[i - N_TRUCK];
        z[0] = 0.0f; z[1] = 0.0f; z[2] = y.x; z[3] = y.y; z[4] = y.z; z[5] = 1.0f;
    }
}

__global__ void k_pairs(const int* __restrict__ src, const int* __restrict__ dst, int P_,
                        const float* __restrict__ s_t, const float4* __restrict__ y4,
                        const float* __restrict__ G, const float* __restrict__ b_lin,
                        float* __restrict__ out) {
    int p = blockIdx.x * blockDim.x + threadIdx.x;
    if (p >= P_) return;
    float zs[6], zd[6];
    load_zf(src[p], s_t, y4, zs);
    load_zf(dst[p], s_t, y4, zd);
    float acc = 0.0f;
#pragma unroll
    for (int a = 0; a < 6; a++) {
        float g = 0.0f;
#pragma unroll
        for (int b = 0; b < 6; b++) g = fmaf(G[a * 6 + b], zd[b], g);
        acc = fmaf(zs[a], g, acc);
    }
    out[p] = acc + b_lin[0];
}

// ============ round-1 fallback (global-atomic path) ============

__global__ void k_G(const float* __restrict__ Wt, const float* __restrict__ bt,
                    const float* __restrict__ Wc, const float* __restrict__ bc,
                    const float* __restrict__ wlin, float* __restrict__ G) {
    int l = threadIdx.x;
    float acc[21];
#pragma unroll
    for (int k = 0; k < 21; k++) acc[k] = 0.0f;
    for (int h = l; h < 128; h += 64) {
        float m[6] = {Wt[h], bt[h], Wc[h], Wc[128 + h], Wc[256 + h], bc[h]};
        float w = wlin[h];
        int k = 0;
#pragma unroll
        for (int a = 0; a < 6; a++)
#pragma unroll
            for (int b = a; b < 6; b++)
                acc[k++] += m[a] * m[b] * w;
    }
    int k = 0;
#pragma unroll
    for (int a = 0; a < 6; a++)
#pragma unroll
        for (int b = a; b < 6; b++) {
            float v = acc[k++];
#pragma unroll
            for (int off = 32; off; off >>= 1) v += __shfl_down(v, off);
            if (l == 0) {
                G[a * 6 + b] = v;
                G[b * 6 + a] = v;
            }
        }
}

__global__ void k_deg(const int* __restrict__ tcol, const int* __restrict__ ccol,
                      const float* __restrict__ ew, int E_,
                      int* __restrict__ cnt_t, float* __restrict__ degw_c) {
    int i = blockIdx.x * blockDim.x + threadIdx.x;
    if (i >= E_) return;
    atomicAdd(&cnt_t[tcol[i]], 1);
    atomicAdd(&degw_c[ccol[i]], ew[i]);
}

__global__ void k_dis(const int* __restrict__ cnt_t, const float* __restrict__ degw_c,
                      float* __restrict__ dis_t, float* __restrict__ dis_c,
                      int nt, int nc) {
    int i = blockIdx.x * blockDim.x + threadIdx.x;
    if (i < nt) dis_t[i] = rsqrtf((float)cnt_t[i] + 1.0f);
    if (i < nc) dis_c[i] = rsqrtf(degw_c[i] + 1.0f);
}

__global__ void k_scat(const int* __restrict__ trow, const int* __restrict__ tcol,
                       const int* __restrict__ crow, const int* __restrict__ ccol,
                       const float* __restrict__ ew, int E_,
                       const float* __restrict__ dis_t, const float* __restrict__ dis_c,
                       const float* __restrict__ x_car,
                       float* __restrict__ sumdis, float* __restrict__ y4) {
    int i = blockIdx.x * blockDim.x + threadIdx.x;
    if (i >= E_) return;
    atomicAdd(&sumdis[tcol[i]], dis_t[trow[i]]);
    int r = crow[i], c = ccol[i];
    float nrm = dis_c[r] * ew[i] * dis_c[c];
    atomicAdd(&y4[c * 4 + 0], nrm * x_car[r * 3 + 0]);
    atomicAdd(&y4[c * 4 + 1], nrm * x_car[r * 3 + 1]);
    atomicAdd(&y4[c * 4 + 2], nrm * x_car[r * 3 + 2]);
}

__global__ void k_fin(int nt, int nc,
                      const float* __restrict__ dis_t, const float* __restrict__ sumdis,
                      float* __restrict__ s_t,
                      const float* __restrict__ dis_c, const float* __restrict__ x_car,
                      float* __restrict__ y4) {
    int i = blockIdx.x * blockDim.x + threadIdx.x;
    if (i < nt) {
        float d = dis_t[i];
        s_t[i] = d * sumdis[i] + d * d;
    }
    if (i < nc) {
        float d2 = dis_c[i] * dis_c[i];
        y4[i * 4 + 0] += d2 * x_car[i * 3 + 0];
        y4[i * 4 + 1] += d2 * x_car[i * 3 + 1];
        y4[i * 4 + 2] += d2 * x_car[i * 3 + 2];
        y4[i * 4 + 3] = 1.0f;
    }
}

// ============ launch ============

extern "C" void kernel_launch(void* const* d_in, const int* in_sizes, int n_in,
                              void* d_out, int out_size, void* d_ws, size_t ws_size,
                              hipStream_t stream) {
    const float* x_car  = (const float*)d_in[0];
    const int*   ei_t   = (const int*)d_in[1];
    const int*   ei_c   = (const int*)d_in[2];
    const float* ew_c   = (const float*)d_in[3];
    const int*   src    = (const int*)d_in[4];
    const int*   dst    = (const int*)d_in[5];
    const float* W_t    = (const float*)d_in[7];
    const float* b_t    = (const float*)d_in[8];
    const float* W_c    = (const float*)d_in[9];
    const float* b_c    = (const float*)d_in[10];
    const float* W_lin  = (const float*)d_in[11];
    const float* b_lin  = (const float*)d_in[12];
    float* out = (float*)d_out;

    const int NC = in_sizes[0] / 3;   // 100000
    const int E_ = in_sizes[1] / 2;   // 1600000
    const int P_ = in_sizes[4];       // 200000

    const int* trow = ei_t;  const int* tcol = ei_t + E_;
    const int* crow = ei_c;  const int* ccol = ei_c + E_;

    char* ws = (char*)d_ws;
    int gP = (P_ + BLK - 1) / BLK;
    int gN = (100096 + 255) / 256;   // covers nt/nc=100000
    int chunk = (E_ + PB - 1) / PB;

    if (ws_size >= WS_NEED_NEW && chunk <= CHUNK_MAX && NB * NPB >= N_TRUCK &&
        NB * NPB >= NC && NB * CAP >= E_ + 8192) {
        int*      curT  = (int*)(ws + 0);
        int*      curC  = (int*)(ws + 1024);
        float*    G     = (float*)(ws + 2048);
        float*    dis_t = (float*)(ws + 4096);
        float*    dis_c = (float*)(ws + 404096);
        float*    s_t   = (float*)(ws + 804096);
        float*    y4    = (float*)(ws + 1204096);
        float4*   xs4   = (float4*)(ws + 2804096);
        unsigned* pT    = (unsigned*)(ws + 4404096);
        u64*      pC8   = (u64*)(ws + 12792704);
        float*    degT4 = (float*)(ws + 29569920);
        float*    degC4 = (float*)(ws + 31171456);
        float*    sum4  = (float*)(ws + 32772992);
        float4*   yp4   = (float4*)(ws + 34374528);

        hipMemsetAsync(ws, 0, 2048, stream);   // cursors
        k_place<<<PB + 1, BLK_PL, 0, stream>>>(trow, tcol, crow, ccol, ew_c, E_,
                                               curT, curC, pT, pC8,
                                               W_t, b_t, W_c, b_c, W_lin, G);
        k_deg4<<<2 * NB * QS, 256, 0, stream>>>(pT, pC8, curT, curC, degT4, degC4);
        k_fin1<<<gN, 256, 0, stream>>>(degT4, degC4, x_car, dis_t, dis_c, xs4,
                                       N_TRUCK, NC);
        k_agg4<<<2 * NB * QS, 256, 0, stream>>>(pT, pC8, curT, curC, dis_t, dis_c,
                                                xs4, sum4, yp4, NC);
        k_fin2<<<gN, 256, 0, stream>>>(sum4, yp4, dis_t, dis_c, xs4,
                                       s_t, (float4*)y4, N_TRUCK, NC);
        k_pairs<<<gP, BLK, 0, stream>>>(src, dst, P_, s_t, (const float4*)y4, G, b_lin, out);
    } else {
        // round-1 global-atomic fallback (~4 MB ws)
        int*   cnt_t  = (int*)(ws + 0);
        float* sumdis = (float*)(ws + 400000);
        float* degw_c = (float*)(ws + 800000);
        float* y4     = (float*)(ws + 1200000);
        float* dis_t  = (float*)(ws + 2800000);
        float* dis_c  = (float*)(ws + 3200000);
        float* s_t    = (float*)(ws + 3600000);
        float* G      = (float*)(ws + 4000000);

        hipMemsetAsync(ws, 0, 2800000, stream);
        int gE = (E_ + BLK - 1) / BLK;
        int gN2 = ((N_TRUCK > NC ? N_TRUCK : NC) + BLK - 1) / BLK;
        k_deg<<<gE, BLK, 0, stream>>>(tcol, ccol, ew_c, E_, cnt_t, degw_c);
        k_dis<<<gN2, BLK, 0, stream>>>(cnt_t, degw_c, dis_t, dis_c, N_TRUCK, NC);
        k_scat<<<gE, BLK, 0, stream>>>(trow, tcol, crow, ccol, ew_c, E_,
                                       dis_t, dis_c, x_car, sumdis, y4);
        k_fin<<<gN2, BLK, 0, stream>>>(N_TRUCK, NC, dis_t, sumdis, s_t, dis_c, x_car, y4);
        k_G<<<1, 64, 0, stream>>>(W_t, b_t, W_c, b_c, W_lin, G);
        k_pairs<<<gP, BLK, 0, stream>>>(src, dst, P_, s_t, (const float4*)y4, G, b_lin, out);
    }
}

// Round 11
// 185.409 us; speedup vs baseline: 1.0317x; 1.0317x over previous
//
#include <hip/hip_runtime.h>

typedef unsigned long long u64;

// Problem constants (fixed by reference file)
#define N_TRUCK 100000
#define BLK 256
#define NB 256           // buckets per graph
#define NPB 391          // nodes per bucket: ceil(100000/256)
#define CAP 8192         // slots per bucket (mean 6250, sigma ~79 -> 24 sigma slack)
#define PB 512           // placer chunks
#define BLK_P 1024       // threads per place/deg/agg block
#define CHUNK_MAX 3136   // >= ceil(E/PB)=3125
#define ROW_MASK 0x1FFFFu
#define LC_SHIFT 17

// ---------------- ws layout (bytes) ----------------
// curT i32[256] @ 0 (1024) | curC i32[256] @ 1024 (1024) | G f32[36] @ 2048
// dis_t @ 4096 | dis_c @ 404096 | s_t @ 804096 | y4 @ 1204096 (1600000)
// xs4 f32x4[100000] @ 2804096 (1600000)
// pT  u32[256*CAP] @ 4404096  (8388608)
// pC8 u64[256*CAP] @ 12792704 (16777216)  ends 29569920
#define WS_NEED_NEW 29569920ULL

// ============ fused place (+G on last block) — round-6 proven ============

__global__ void k_place(const int* __restrict__ trow, const int* __restrict__ tcol,
                        const int* __restrict__ crow, const int* __restrict__ ccol,
                        const float* __restrict__ ew, int E_,
                        int* __restrict__ curT, int* __restrict__ curC,
                        unsigned* __restrict__ pT, u64* __restrict__ pC8,
                        const float* __restrict__ Wt, const float* __restrict__ bt,
                        const float* __restrict__ Wc, const float* __restrict__ bc,
                        const float* __restrict__ wlin, float* __restrict__ G) {
    if (blockIdx.x == PB) {
        // fused k_G: G[a][b] = sum_h M[a,h]*M[b,h]*wlin[h]
        int l = threadIdx.x;
        if (l < 64) {
            float acc[21];
#pragma unroll
            for (int k = 0; k < 21; k++) acc[k] = 0.0f;
            for (int h = l; h < 128; h += 64) {
                float m[6] = {Wt[h], bt[h], Wc[h], Wc[128 + h], Wc[256 + h], bc[h]};
                float w = wlin[h];
                int k = 0;
#pragma unroll
                for (int a = 0; a < 6; a++)
#pragma unroll
                    for (int b2 = a; b2 < 6; b2++)
                        acc[k++] += m[a] * m[b2] * w;
            }
            int k = 0;
#pragma unroll
            for (int a = 0; a < 6; a++)
#pragma unroll
                for (int b2 = a; b2 < 6; b2++) {
                    float v = acc[k++];
#pragma unroll
                    for (int off = 32; off; off >>= 1) v += __shfl_down(v, off);
                    if (l == 0) {
                        G[a * 6 + b2] = v;
                        G[b2 * 6 + a] = v;
                    }
                }
        }
        return;
    }

    __shared__ u64 pay8[CHUNK_MAX];          // car payload; truck reuses as u32[]
    __shared__ unsigned char bkt[CHUNK_MAX];
    __shared__ int hist[NB];                 // hist -> local cursor
    __shared__ int shiftA[NB];               // scan temp -> flush shift
    unsigned* pay4 = (unsigned*)pay8;

    int b = blockIdx.x;
    int chunk = (E_ + PB - 1) / PB;
    int s0 = b * chunk, s1 = min(E_, s0 + chunk);
    int n = s1 - s0;
    int t = threadIdx.x;

    // ================= truck graph =================
    for (int k = t; k < NB; k += BLK_P) hist[k] = 0;
    __syncthreads();
    for (int j = s0 + t; j < s1; j += BLK_P) atomicAdd(&hist[tcol[j] / NPB], 1);
    __syncthreads();
    int myCnt = (t < NB) ? hist[t] : 0;
    if (t < NB) shiftA[t] = myCnt;
    __syncthreads();
    for (int off = 1; off < NB; off <<= 1) {
        int x = (t < NB && t >= off) ? shiftA[t - off] : 0;
        __syncthreads();
        if (t < NB) shiftA[t] += x;
        __syncthreads();
    }
    if (t < NB) {
        int excl = shiftA[t] - myCnt;                      // local exclusive base
        int gstart = t * CAP + atomicAdd(&curT[t], myCnt); // global run start
        shiftA[t] = gstart - excl;
        hist[t] = excl;                                    // local cursor
    }
    __syncthreads();
    for (int j = s0 + t; j < s1; j += BLK_P) {
        int tc = tcol[j];
        int k = tc / NPB;
        int s = atomicAdd(&hist[k], 1);
        pay4[s] = ((unsigned)(tc - k * NPB) << LC_SHIFT) | (unsigned)trow[j];
        bkt[s] = (unsigned char)k;
    }
    __syncthreads();
    for (int s = t; s < n; s += BLK_P)
        pT[s + shiftA[bkt[s]]] = pay4[s];
    __syncthreads();

    // ================= car graph =================
    for (int k = t; k < NB; k += BLK_P) hist[k] = 0;
    __syncthreads();
    for (int j = s0 + t; j < s1; j += BLK_P) atomicAdd(&hist[ccol[j] / NPB], 1);
    __syncthreads();
    myCnt = (t < NB) ? hist[t] : 0;
    if (t < NB) shiftA[t] = myCnt;
    __syncthreads();
    for (int off = 1; off < NB; off <<= 1) {
        int x = (t < NB && t >= off) ? shiftA[t - off] : 0;
        __syncthreads();
        if (t < NB) shiftA[t] += x;
        __syncthreads();
    }
    if (t < NB) {
        int excl = shiftA[t] - myCnt;
        int gstart = t * CAP + atomicAdd(&curC[t], myCnt);
        shiftA[t] = gstart - excl;
        hist[t] = excl;
    }
    __syncthreads();
    for (int j = s0 + t; j < s1; j += BLK_P) {
        int cc = ccol[j];
        int k = cc / NPB;
        int s = atomicAdd(&hist[k], 1);
        unsigned lo = ((unsigned)(cc - k * NPB) << LC_SHIFT) | (unsigned)crow[j];
        pay8[s] = ((u64)__float_as_uint(ew[j]) << 32) | lo;
        bkt[s] = (unsigned char)k;
    }
    __syncthreads();
    for (int s = t; s < n; s += BLK_P)
        pC8[s + shiftA[bkt[s]]] = pay8[s];
}

// ============ per-bucket degree -> dis (+xs4 for car); 2*NB blocks ============

__global__ void k_deg2(const unsigned* __restrict__ pT, const u64* __restrict__ pC8,
                       const int* __restrict__ curT, const int* __restrict__ curC,
                       const float* __restrict__ x_car,
                       float* __restrict__ dis_t, float* __restrict__ dis_c,
                       float4* __restrict__ xs4, int nt, int nc) {
    __shared__ float acc[NPB];
    int b = blockIdx.x;
    bool car = b >= NB;
    int bk = car ? b - NB : b;
    int cnt = car ? curC[bk] : curT[bk];
    int s0 = bk * CAP;
    for (int k = threadIdx.x; k < NPB; k += blockDim.x) acc[k] = 0.0f;
    __syncthreads();
    if (car) {
        const ulonglong2* p2 = (const ulonglong2*)(pC8 + s0);
        int half = cnt >> 1;
        for (int j = threadIdx.x; j < half; j += blockDim.x) {
            ulonglong2 v = p2[j];
            atomicAdd(&acc[((unsigned)v.x) >> LC_SHIFT], __uint_as_float((unsigned)(v.x >> 32)));
            atomicAdd(&acc[((unsigned)v.y) >> LC_SHIFT], __uint_as_float((unsigned)(v.y >> 32)));
        }
        if ((cnt & 1) && threadIdx.x == 0) {
            u64 v = pC8[s0 + cnt - 1];
            atomicAdd(&acc[((unsigned)v) >> LC_SHIFT], __uint_as_float((unsigned)(v >> 32)));
        }
    } else {
        const uint2* p2 = (const uint2*)(pT + s0);
        int half = cnt >> 1;
        for (int j = threadIdx.x; j < half; j += blockDim.x) {
            uint2 v = p2[j];
            atomicAdd(&acc[v.x >> LC_SHIFT], 1.0f);
            atomicAdd(&acc[v.y >> LC_SHIFT], 1.0f);
        }
        if ((cnt & 1) && threadIdx.x == 0)
            atomicAdd(&acc[pT[s0 + cnt - 1] >> LC_SHIFT], 1.0f);
    }
    __syncthreads();
    int ntot = car ? nc : nt;
    for (int nn = threadIdx.x; nn < NPB; nn += blockDim.x) {
        int node = bk * NPB + nn;
        if (node < ntot) {
            float d = rsqrtf(acc[nn] + 1.0f);
            if (car) {
                dis_c[node] = d;
                const float* xn = &x_car[3 * node];
                xs4[node] = make_float4(d * xn[0], d * xn[1], d * xn[2], d);
            } else {
                dis_t[node] = d;
            }
        }
    }
}

// ============ per-bucket aggregation -> s_t / y4 (2*NB blocks) ============

__global__ void k_agg(const unsigned* __restrict__ pT, const u64* __restrict__ pC8,
                      const int* __restrict__ curT, const int* __restrict__ curC,
                      const float* __restrict__ dis_t, const float* __restrict__ dis_c,
                      const float4* __restrict__ xs4,
                      float* __restrict__ s_t, float4* __restrict__ y4,
                      int nt, int nc) {
    int b = blockIdx.x;
    if (b < NB) {
        __shared__ float sacc[NPB];
        int cnt = curT[b];
        int s0 = b * CAP;
        for (int k = threadIdx.x; k < NPB; k += blockDim.x) sacc[k] = 0.0f;
        __syncthreads();
        const uint2* p2 = (const uint2*)(pT + s0);
        int half = cnt >> 1;
        for (int j = threadIdx.x; j < half; j += blockDim.x) {
            uint2 v = p2[j];
            float da = dis_t[v.x & ROW_MASK];
            float db = dis_t[v.y & ROW_MASK];
            atomicAdd(&sacc[v.x >> LC_SHIFT], da);
            atomicAdd(&sacc[v.y >> LC_SHIFT], db);
        }
        if ((cnt & 1) && threadIdx.x == 0) {
            unsigned v = pT[s0 + cnt - 1];
            atomicAdd(&sacc[v >> LC_SHIFT], dis_t[v & ROW_MASK]);
        }
        __syncthreads();
        for (int nn = threadIdx.x; nn < NPB; nn += blockDim.x) {
            int node = b * NPB + nn;
            if (node < nt) {
                float d = dis_t[node];
                s_t[node] = fmaf(d, sacc[nn], d * d);
            }
        }
    } else {
        int bk = b - NB;
        __shared__ float y[NPB * 5];   // stride 5: avoid stride-4 bank aliasing
        __shared__ float dcl[NPB];
        int cnt = curC[bk];
        int s0 = bk * CAP;
        for (int k = threadIdx.x; k < NPB * 5; k += blockDim.x) y[k] = 0.0f;
        for (int k = threadIdx.x; k < NPB; k += blockDim.x) {
            int node = bk * NPB + k;
            dcl[k] = (node < nc) ? dis_c[node] : 0.0f;
        }
        __syncthreads();
        const ulonglong2* p2 = (const ulonglong2*)(pC8 + s0);
        int half = cnt >> 1;
        for (int j = threadIdx.x; j < half; j += blockDim.x) {
            ulonglong2 v = p2[j];
            unsigned loa = (unsigned)v.x, lob = (unsigned)v.y;
            float4 xa = xs4[loa & ROW_MASK];     // dis_c[r] pre-folded
            float4 xb = xs4[lob & ROW_MASK];
            int lca = loa >> LC_SHIFT, lcb = lob >> LC_SHIFT;
            float na = __uint_as_float((unsigned)(v.x >> 32)) * dcl[lca];
            float nb = __uint_as_float((unsigned)(v.y >> 32)) * dcl[lcb];
            atomicAdd(&y[lca * 5 + 0], na * xa.x);
            atomicAdd(&y[lca * 5 + 1], na * xa.y);
            atomicAdd(&y[lca * 5 + 2], na * xa.z);
            atomicAdd(&y[lcb * 5 + 0], nb * xb.x);
            atomicAdd(&y[lcb * 5 + 1], nb * xb.y);
            atomicAdd(&y[lcb * 5 + 2], nb * xb.z);
        }
        if ((cnt & 1) && threadIdx.x == 0) {
            u64 v = pC8[s0 + cnt - 1];
            unsigned lo = (unsigned)v;
            float4 xa = xs4[lo & ROW_MASK];
            int lc = lo >> LC_SHIFT;
            float na = __uint_as_float((unsigned)(v >> 32)) * dcl[lc];
            atomicAdd(&y[lc * 5 + 0], na * xa.x);
            atomicAdd(&y[lc * 5 + 1], na * xa.y);
            atomicAdd(&y[lc * 5 + 2], na * xa.z);
        }
        __syncthreads();
        for (int nn = threadIdx.x; nn < NPB; nn += blockDim.x) {
            int node = bk * NPB + nn;
            if (node < nc) {
                float d = dcl[nn];
                float4 xs = xs4[node];           // d*x already
                y4[node] = make_float4(fmaf(d, xs.x, y[nn * 5 + 0]),
                                       fmaf(d, xs.y, y[nn * 5 + 1]),
                                       fmaf(d, xs.z, y[nn * 5 + 2]), 1.0f);
            }
        }
    }
}

// ============ pair scorer ============

__device__ __forceinline__ void load_zf(int i, const float* __restrict__ s_t,
                                        const float4* __restrict__ y4, float z[6]) {
    if (i < N_TRUCK) {
        z[0] = s_t[i]; z[1] = 1.0f; z[2] = 0.0f; z[3] = 0.0f; z[4] = 0.0f; z[5] = 0.0f;
    } else {
        float4 y = y4[i - N_TRUCK];
        z[0] = 0.0f; z[1] = 0.0f; z[2] = y.x; z[3] = y.y; z[4] = y.z; z[5] = 1.0f;
    }
}

__global__ void k_pairs(const int* __restrict__ src, const int* __restrict__ dst, int P_,
                        const float* __restrict__ s_t, const float4* __restrict__ y4,
                        const float* __restrict__ G, const float* __restrict__ b_lin,
                        float* __restrict__ out) {
    int p = blockIdx.x * blockDim.x + threadIdx.x;
    if (p >= P_) return;
    float zs[6], zd[6];
    load_zf(src[p], s_t, y4, zs);
    load_zf(dst[p], s_t, y4, zd);
    float acc = 0.0f;
#pragma unroll
    for (int a = 0; a < 6; a++) {
        float g = 0.0f;
#pragma unroll
        for (int b = 0; b < 6; b++) g = fmaf(G[a * 6 + b], zd[b], g);
        acc = fmaf(zs[a], g, acc);
    }
    out[p] = acc + b_lin[0];
}

// ============ round-1 fallback (global-atomic path) ============

__global__ void k_G(const float* __restrict__ Wt, const float* __restrict__ bt,
                    const float* __restrict__ Wc, const float* __restrict__ bc,
                    const float* __restrict__ wlin, float* __restrict__ G) {
    int l = threadIdx.x;
    float acc[21];
#pragma unroll
    for (int k = 0; k < 21; k++) acc[k] = 0.0f;
    for (int h = l; h < 128; h += 64) {
        float m[6] = {Wt[h], bt[h], Wc[h], Wc[128 + h], Wc[256 + h], bc[h]};
        float w = wlin[h];
        int k = 0;
#pragma unroll
        for (int a = 0; a < 6; a++)
#pragma unroll
            for (int b = a; b < 6; b++)
                acc[k++] += m[a] * m[b] * w;
    }
    int k = 0;
#pragma unroll
    for (int a = 0; a < 6; a++)
#pragma unroll
        for (int b = a; b < 6; b++) {
            float v = acc[k++];
#pragma unroll
            for (int off = 32; off; off >>= 1) v += __shfl_down(v, off);
            if (l == 0) {
                G[a * 6 + b] = v;
                G[b * 6 + a] = v;
            }
        }
}

__global__ void k_deg(const int* __restrict__ tcol, const int* __restrict__ ccol,
                      const float* __restrict__ ew, int E_,
                      int* __restrict__ cnt_t, float* __restrict__ degw_c) {
    int i = blockIdx.x * blockDim.x + threadIdx.x;
    if (i >= E_) return;
    atomicAdd(&cnt_t[tcol[i]], 1);
    atomicAdd(&degw_c[ccol[i]], ew[i]);
}

__global__ void k_dis(const int* __restrict__ cnt_t, const float* __restrict__ degw_c,
                      float* __restrict__ dis_t, float* __restrict__ dis_c,
                      int nt, int nc) {
    int i = blockIdx.x * blockDim.x + threadIdx.x;
    if (i < nt) dis_t[i] = rsqrtf((float)cnt_t[i] + 1.0f);
    if (i < nc) dis_c[i] = rsqrtf(degw_c[i] + 1.0f);
}

__global__ void k_scat(const int* __restrict__ trow, const int* __restrict__ tcol,
                       const int* __restrict__ crow, const int* __restrict__ ccol,
                       const float* __restrict__ ew, int E_,
                       const float* __restrict__ dis_t, const float* __restrict__ dis_c,
                       const float* __restrict__ x_car,
                       float* __restrict__ sumdis, float* __restrict__ y4) {
    int i = blockIdx.x * blockDim.x + threadIdx.x;
    if (i >= E_) return;
    atomicAdd(&sumdis[tcol[i]], dis_t[trow[i]]);
    int r = crow[i], c = ccol[i];
    float nrm = dis_c[r] * ew[i] * dis_c[c];
    atomicAdd(&y4[c * 4 + 0], nrm * x_car[r * 3 + 0]);
    atomicAdd(&y4[c * 4 + 1], nrm * x_car[r * 3 + 1]);
    atomicAdd(&y4[c * 4 + 2], nrm * x_car[r * 3 + 2]);
}

__global__ void k_fin(int nt, int nc,
                      const float* __restrict__ dis_t, const float* __restrict__ sumdis,
                      float* __restrict__ s_t,
                      const float* __restrict__ dis_c, const float* __restrict__ x_car,
                      float* __restrict__ y4) {
    int i = blockIdx.x * blockDim.x + threadIdx.x;
    if (i < nt) {
        float d = dis_t[i];
        s_t[i] = d * sumdis[i] + d * d;
    }
    if (i < nc) {
        float d2 = dis_c[i] * dis_c[i];
        y4[i * 4 + 0] += d2 * x_car[i * 3 + 0];
        y4[i * 4 + 1] += d2 * x_car[i * 3 + 1];
        y4[i * 4 + 2] += d2 * x_car[i * 3 + 2];
        y4[i * 4 + 3] = 1.0f;
    }
}

// ============ launch ============

extern "C" void kernel_launch(void* const* d_in, const int* in_sizes, int n_in,
                              void* d_out, int out_size, void* d_ws, size_t ws_size,
                              hipStream_t stream) {
    const float* x_car  = (const float*)d_in[0];
    const int*   ei_t   = (const int*)d_in[1];
    const int*   ei_c   = (const int*)d_in[2];
    const float* ew_c   = (const float*)d_in[3];
    const int*   src    = (const int*)d_in[4];
    const int*   dst    = (const int*)d_in[5];
    const float* W_t    = (const float*)d_in[7];
    const float* b_t    = (const float*)d_in[8];
    const float* W_c    = (const float*)d_in[9];
    const float* b_c    = (const float*)d_in[10];
    const float* W_lin  = (const float*)d_in[11];
    const float* b_lin  = (const float*)d_in[12];
    float* out = (float*)d_out;

    const int NC = in_sizes[0] / 3;   // 100000
    const int E_ = in_sizes[1] / 2;   // 1600000
    const int P_ = in_sizes[4];       // 200000

    const int* trow = ei_t;  const int* tcol = ei_t + E_;
    const int* crow = ei_c;  const int* ccol = ei_c + E_;

    char* ws = (char*)d_ws;
    int gP = (P_ + BLK - 1) / BLK;
    int chunk = (E_ + PB - 1) / PB;

    if (ws_size >= WS_NEED_NEW && chunk <= CHUNK_MAX && NB * NPB >= N_TRUCK &&
        NB * NPB >= NC && NB * CAP >= E_ + 8192) {
        int*      curT  = (int*)(ws + 0);
        int*      curC  = (int*)(ws + 1024);
        float*    G     = (float*)(ws + 2048);
        float*    dis_t = (float*)(ws + 4096);
        float*    dis_c = (float*)(ws + 404096);
        float*    s_t   = (float*)(ws + 804096);
        float*    y4    = (float*)(ws + 1204096);
        float4*   xs4   = (float4*)(ws + 2804096);
        unsigned* pT    = (unsigned*)(ws + 4404096);
        u64*      pC8   = (u64*)(ws + 12792704);

        hipMemsetAsync(ws, 0, 2048, stream);   // cursors
        k_place<<<PB + 1, BLK_P, 0, stream>>>(trow, tcol, crow, ccol, ew_c, E_,
                                              curT, curC, pT, pC8,
                                              W_t, b_t, W_c, b_c, W_lin, G);
        k_deg2<<<2 * NB, BLK_P, 0, stream>>>(pT, pC8, curT, curC, x_car,
                                             dis_t, dis_c, xs4, N_TRUCK, NC);
        k_agg<<<2 * NB, BLK_P, 0, stream>>>(pT, pC8, curT, curC, dis_t, dis_c,
                                            xs4, s_t, (float4*)y4, N_TRUCK, NC);
        k_pairs<<<gP, BLK, 0, stream>>>(src, dst, P_, s_t, (const float4*)y4, G, b_lin, out);
    } else {
        // round-1 global-atomic fallback (~4 MB ws)
        int*   cnt_t  = (int*)(ws + 0);
        float* sumdis = (float*)(ws + 400000);
        float* degw_c = (float*)(ws + 800000);
        float* y4     = (float*)(ws + 1200000);
        float* dis_t  = (float*)(ws + 2800000);
        float* dis_c  = (float*)(ws + 3200000);
        float* s_t    = (float*)(ws + 3600000);
        float* G      = (float*)(ws + 4000000);

        hipMemsetAsync(ws, 0, 2800000, stream);
        int gE = (E_ + BLK - 1) / BLK;
        int gN = ((N_TRUCK > NC ? N_TRUCK : NC) + BLK - 1) / BLK;
        k_deg<<<gE, BLK, 0, stream>>>(tcol, ccol, ew_c, E_, cnt_t, degw_c);
        k_dis<<<gN, BLK, 0, stream>>>(cnt_t, degw_c, dis_t, dis_c, N_TRUCK, NC);
        k_scat<<<gE, BLK, 0, stream>>>(trow, tcol, crow, ccol, ew_c, E_,
                                       dis_t, dis_c, x_car, sumdis, y4);
        k_fin<<<gN, BLK, 0, stream>>>(N_TRUCK, NC, dis_t, sumdis, s_t, dis_c, x_car, y4);
        k_G<<<1, 64, 0, stream>>>(W_t, b_t, W_c, b_c, W_lin, G);
        k_pairs<<<gP, BLK, 0, stream>>>(src, dst, P_, s_t, (const float4*)y4, G, b_lin, out);
    }
}